// Round 2
// baseline (13733.791 us; speedup 1.0000x reference)
//
#include <hip/hip_runtime.h>
#include <hip/hip_bf16.h>

// Problem constants: B=64, T=512, I=1024, H=1024 (fp32 in/out).
#define BB_   64
#define TT_   512
#define II_   1024
#define HH_   1024

typedef _Float16 half8  __attribute__((ext_vector_type(8)));
typedef _Float16 half4v __attribute__((ext_vector_type(4)));
typedef float    f32x4  __attribute__((ext_vector_type(4)));

// ---------------------------------------------------------------------------
// Phase 1: xp[b*T+t][j] = x[b,t,:] . W_ih[j,:] + b_ih[j], written to d_out.
// 128x128 tile, BK=32, f16 MFMA 16x16x32, in-staging fp32->f16 convert.
// Fragment layouts (HW-verified per guide):
//   A: A[m=lane&15][k=(lane>>4)*8+e]   B: B[k=(lane>>4)*8+e][n=lane&15]
//   D: row=(lane>>4)*4+reg, col=lane&15
// ---------------------------------------------------------------------------
__global__ __launch_bounds__(256) void gemm_xp(const float* __restrict__ x,
                                               const float* __restrict__ Wih,
                                               const float* __restrict__ bih,
                                               float* __restrict__ out) {
    __shared__ alignas(16) _Float16 As[128 * 40];   // row stride 40 elems (80 B)
    __shared__ alignas(16) _Float16 Bs[128 * 40];

    const int tid  = threadIdx.x;
    const int bm   = blockIdx.x >> 3;              // 256 m-tiles
    const int bn   = blockIdx.x & 7;               // 8 n-tiles
    const int M0   = bm * 128, N0 = bn * 128;
    const int lane = tid & 63, w = tid >> 6;
    const int wm   = (w & 1) * 64, wn = (w >> 1) * 64;   // wave quadrant
    const int ro   = lane & 15, q = lane >> 4;
    const int sr   = tid >> 3, sc = tid & 7;       // staging: 32 rows x 8 chunks

    const f32x4 zero4 = {0.f, 0.f, 0.f, 0.f};
    f32x4 acc[4][4];
    #pragma unroll
    for (int i = 0; i < 4; ++i)
        #pragma unroll
        for (int j = 0; j < 4; ++j) acc[i][j] = zero4;

    for (int kk = 0; kk < 32; ++kk) {
        const int k0 = kk * 32;
        #pragma unroll
        for (int ir = 0; ir < 4; ++ir) {
            const int row = ir * 32 + sr;
            const float4 av = *(const float4*)(x   + (size_t)(M0 + row) * II_ + k0 + sc * 4);
            const float4 bv = *(const float4*)(Wih + (size_t)(N0 + row) * II_ + k0 + sc * 4);
            half4v ah = { (_Float16)av.x, (_Float16)av.y, (_Float16)av.z, (_Float16)av.w };
            half4v bh = { (_Float16)bv.x, (_Float16)bv.y, (_Float16)bv.z, (_Float16)bv.w };
            *(half4v*)(As + row * 40 + sc * 4) = ah;
            *(half4v*)(Bs + row * 40 + sc * 4) = bh;
        }
        __syncthreads();

        half8 a[4], b[4];
        #pragma unroll
        for (int i = 0; i < 4; ++i) {
            a[i] = *(const half8*)(As + (wm + i * 16 + ro) * 40 + q * 8);
            b[i] = *(const half8*)(Bs + (wn + i * 16 + ro) * 40 + q * 8);
        }
        #pragma unroll
        for (int i = 0; i < 4; ++i)
            #pragma unroll
            for (int j = 0; j < 4; ++j)
                acc[i][j] = __builtin_amdgcn_mfma_f32_16x16x32_f16(a[i], b[j], acc[i][j], 0, 0, 0);
        __syncthreads();
    }

    #pragma unroll
    for (int j = 0; j < 4; ++j) {
        const int col = N0 + wn + j * 16 + ro;
        const float bias = bih[col];
        #pragma unroll
        for (int i = 0; i < 4; ++i) {
            #pragma unroll
            for (int r = 0; r < 4; ++r) {
                const int rowg = M0 + wm + i * 16 + q * 4 + r;
                out[(size_t)rowg * HH_ + col] = acc[i][j][r] + bias;
            }
        }
    }
}

// ---------------------------------------------------------------------------
// Phase 2: persistent recurrence. 256 blocks x 256 threads = 16 groups x 16
// WGs; plain launch (256 blocks on 256 CUs, __launch_bounds__(256,1) => >=1
// block/CU resources; de-facto co-resident). Group g owns batches 4g..4g+3;
// WG wg owns cols j0=64*wg..+63 and holds its 64x1024 W_hh slice as 32 MFMA
// B-fragments in VGPRs. h_{s-1} is read in fp32 straight from `out` rows
// t=s-1 (h0 input at s=0) -- no separate h buffer, d_ws holds only flags.
// Per step: group flag-barrier, stage h (fp32->f16) into LDS, 32 MFMAs/wave
// over a 256-wide k-slice, LDS reduce across the 4 waves, tanh, store fp32
// h into out (overwriting xp in place), release-post flag.
// ---------------------------------------------------------------------------
__global__ __launch_bounds__(256, 1) void rnn_steps(const float* __restrict__ Whh,
                                                    const float* __restrict__ bhh,
                                                    const float* __restrict__ h0,
                                                    float* __restrict__ out,
                                                    int* __restrict__ flags) {
    __shared__ alignas(16) _Float16 h_lds[5 * 1032]; // rows 0..3 batches, row 4 zeros
    __shared__ float red[4][4][64];                  // [k-slice wave][b][j]

    const int tid  = threadIdx.x;
    const int lane = tid & 63;
    const int w    = tid >> 6;             // wave id == k-slice id == epilogue batch id
    const int g    = blockIdx.x >> 4;      // group 0..15
    const int wg   = blockIdx.x & 15;      // wg within group
    const int b0   = g * 4;
    const int j0   = wg * 64;
    const int ro   = lane & 15, q = lane >> 4;
    const int kbase = w * 256;
    const int arow  = (ro < 4) ? ro : 4;   // A rows >=4 read the shared zero row

    // Preload W_hh B-fragments: wf[nt][ks] holds B[k][n] = Whh[j0+n][k],
    // n = nt*16 + ro, k = kbase + ks*32 + q*8 + e.
    half8 wf[4][8];
    #pragma unroll
    for (int nt = 0; nt < 4; ++nt) {
        const float* wrow = Whh + (size_t)(j0 + nt * 16 + ro) * HH_;
        #pragma unroll
        for (int ks = 0; ks < 8; ++ks) {
            const int kc = kbase + ks * 32 + q * 8;
            const float4 w0 = *(const float4*)(wrow + kc);
            const float4 w1 = *(const float4*)(wrow + kc + 4);
            half8 hv;
            hv[0] = (_Float16)w0.x; hv[1] = (_Float16)w0.y;
            hv[2] = (_Float16)w0.z; hv[3] = (_Float16)w0.w;
            hv[4] = (_Float16)w1.x; hv[5] = (_Float16)w1.y;
            hv[6] = (_Float16)w1.z; hv[7] = (_Float16)w1.w;
            wf[nt][ks] = hv;
        }
    }
    const float bhh_r = bhh[j0 + lane];

    for (int i = tid; i < 1032; i += 256) h_lds[4 * 1032 + i] = (_Float16)0.f;
    __syncthreads();

    int* myflags = flags + g * 16 * 16;    // 16 ints (64 B) spacing per WG

    const int srow = tid >> 6;             // staging: batch row 0..3
    const int scol = (tid & 63) * 16;      // 16 floats per thread

    const f32x4 zero4 = {0.f, 0.f, 0.f, 0.f};

    for (int s = 0; s < TT_; ++s) {
        // ---- group barrier: wait until all 16 peers finished step s-1 ----
        if (s > 0) {
            if (w == 0 && lane < 16) {
                while (__hip_atomic_load(myflags + lane * 16, __ATOMIC_ACQUIRE,
                                         __HIP_MEMORY_SCOPE_AGENT) < s)
                    __builtin_amdgcn_s_sleep(1);
            }
            __syncthreads();
        }

        // ---- stage h_{s-1} (fp32 from out rows t=s-1, or h0) into LDS ----
        {
            const float* hsrc = (s == 0)
                ? (h0 + (size_t)(b0 + srow) * HH_ + scol)
                : (out + ((size_t)(b0 + srow) * TT_ + (s - 1)) * HH_ + scol);
            const float4 f0 = *(const float4*)(hsrc);
            const float4 f1 = *(const float4*)(hsrc + 4);
            const float4 f2 = *(const float4*)(hsrc + 8);
            const float4 f3 = *(const float4*)(hsrc + 12);
            half8 hv0, hv1;
            hv0[0] = (_Float16)f0.x; hv0[1] = (_Float16)f0.y;
            hv0[2] = (_Float16)f0.z; hv0[3] = (_Float16)f0.w;
            hv0[4] = (_Float16)f1.x; hv0[5] = (_Float16)f1.y;
            hv0[6] = (_Float16)f1.z; hv0[7] = (_Float16)f1.w;
            hv1[0] = (_Float16)f2.x; hv1[1] = (_Float16)f2.y;
            hv1[2] = (_Float16)f2.z; hv1[3] = (_Float16)f2.w;
            hv1[4] = (_Float16)f3.x; hv1[5] = (_Float16)f3.y;
            hv1[6] = (_Float16)f3.z; hv1[7] = (_Float16)f3.w;
            _Float16* dst = h_lds + srow * 1032 + scol;
            *(half8*)dst = hv0;
            *(half8*)(dst + 8) = hv1;
        }
        // prefetch xp for the epilogue (this thread's own output address)
        const float xpv = out[((size_t)(b0 + w) * TT_ + s) * HH_ + j0 + lane];
        __syncthreads();

        // ---- MFMA: pre[b][j] partials over this wave's 256-wide k-slice ----
        f32x4 acc[4] = {zero4, zero4, zero4, zero4};
        #pragma unroll
        for (int ks = 0; ks < 8; ++ks) {
            const half8 a = *(const half8*)(h_lds + arow * 1032 + kbase + ks * 32 + q * 8);
            #pragma unroll
            for (int nt = 0; nt < 4; ++nt)
                acc[nt] = __builtin_amdgcn_mfma_f32_16x16x32_f16(a, wf[nt][ks], acc[nt], 0, 0, 0);
        }
        // D layout: row=(q*4+reg) => batches 0..3 live in q==0 lanes, col=nt*16+ro
        if (q == 0) {
            #pragma unroll
            for (int nt = 0; nt < 4; ++nt)
                #pragma unroll
                for (int r = 0; r < 4; ++r)
                    red[w][r][nt * 16 + ro] = acc[nt][r];
        }
        __syncthreads();

        // ---- epilogue: thread -> (batch w, col j0+lane) ----
        const float pre  = xpv + bhh_r + red[0][w][lane] + red[1][w][lane]
                                        + red[2][w][lane] + red[3][w][lane];
        const float hnew = tanhf(pre);
        out[((size_t)(b0 + w) * TT_ + s) * HH_ + j0 + lane] = hnew;

        __threadfence();          // device-scope release of h writes
        __syncthreads();          // all threads' fences done before posting
        if (tid == 0)
            __hip_atomic_store(myflags + wg * 16, s + 1, __ATOMIC_RELEASE,
                               __HIP_MEMORY_SCOPE_AGENT);
    }
}

// ---------------------------------------------------------------------------
extern "C" void kernel_launch(void* const* d_in, const int* in_sizes, int n_in,
                              void* d_out, int out_size, void* d_ws, size_t ws_size,
                              hipStream_t stream) {
    (void)in_sizes; (void)n_in; (void)out_size; (void)ws_size;

    const float* x   = (const float*)d_in[0];
    const float* h0  = (const float*)d_in[1];
    const float* Wih = (const float*)d_in[2];
    const float* bih = (const float*)d_in[3];
    const float* Whh = (const float*)d_in[4];
    const float* bhh = (const float*)d_in[5];
    float* out = (float*)d_out;

    // d_ws: flags only -- 256 WGs * 16 ints (64 B spacing) = 16 KB.
    // Poisoned 0xAA => negative ints => "not yet posted" for every step. OK.
    int* flags = (int*)d_ws;

    gemm_xp<<<2048, 256, 0, stream>>>(x, Wih, bih, out);
    rnn_steps<<<256, 256, 0, stream>>>(Whh, bhh, h0, out, flags);
}

// Round 3
// 2538.582 us; speedup vs baseline: 5.4100x; 5.4100x over previous
//
#include <hip/hip_runtime.h>
#include <hip/hip_bf16.h>

// Problem constants: B=64, T=512, I=1024, H=1024 (fp32 in/out).
#define BB_   64
#define TT_   512
#define II_   1024
#define HH_   1024

typedef _Float16 half8  __attribute__((ext_vector_type(8)));
typedef _Float16 half4v __attribute__((ext_vector_type(4)));
typedef float    f32x4  __attribute__((ext_vector_type(4)));

// ---------------------------------------------------------------------------
// Phase 1: xp[b*T+t][j] = x[b,t,:] . W_ih[j,:] + b_ih[j], written to d_out.
// 128x128 tile, BK=32, f16 MFMA 16x16x32, in-staging fp32->f16 convert.
// ---------------------------------------------------------------------------
__global__ __launch_bounds__(256) void gemm_xp(const float* __restrict__ x,
                                               const float* __restrict__ Wih,
                                               const float* __restrict__ bih,
                                               float* __restrict__ out) {
    __shared__ alignas(16) _Float16 As[128 * 40];   // row stride 40 elems (80 B)
    __shared__ alignas(16) _Float16 Bs[128 * 40];

    const int tid  = threadIdx.x;
    const int bm   = blockIdx.x >> 3;              // 256 m-tiles
    const int bn   = blockIdx.x & 7;               // 8 n-tiles
    const int M0   = bm * 128, N0 = bn * 128;
    const int lane = tid & 63, w = tid >> 6;
    const int wm   = (w & 1) * 64, wn = (w >> 1) * 64;   // wave quadrant
    const int ro   = lane & 15, q = lane >> 4;
    const int sr   = tid >> 3, sc = tid & 7;       // staging: 32 rows x 8 chunks

    const f32x4 zero4 = {0.f, 0.f, 0.f, 0.f};
    f32x4 acc[4][4];
    #pragma unroll
    for (int i = 0; i < 4; ++i)
        #pragma unroll
        for (int j = 0; j < 4; ++j) acc[i][j] = zero4;

    for (int kk = 0; kk < 32; ++kk) {
        const int k0 = kk * 32;
        #pragma unroll
        for (int ir = 0; ir < 4; ++ir) {
            const int row = ir * 32 + sr;
            const float4 av = *(const float4*)(x   + (size_t)(M0 + row) * II_ + k0 + sc * 4);
            const float4 bv = *(const float4*)(Wih + (size_t)(N0 + row) * II_ + k0 + sc * 4);
            half4v ah = { (_Float16)av.x, (_Float16)av.y, (_Float16)av.z, (_Float16)av.w };
            half4v bh = { (_Float16)bv.x, (_Float16)bv.y, (_Float16)bv.z, (_Float16)bv.w };
            *(half4v*)(As + row * 40 + sc * 4) = ah;
            *(half4v*)(Bs + row * 40 + sc * 4) = bh;
        }
        __syncthreads();

        half8 a[4], b[4];
        #pragma unroll
        for (int i = 0; i < 4; ++i) {
            a[i] = *(const half8*)(As + (wm + i * 16 + ro) * 40 + q * 8);
            b[i] = *(const half8*)(Bs + (wn + i * 16 + ro) * 40 + q * 8);
        }
        #pragma unroll
        for (int i = 0; i < 4; ++i)
            #pragma unroll
            for (int j = 0; j < 4; ++j)
                acc[i][j] = __builtin_amdgcn_mfma_f32_16x16x32_f16(a[i], b[j], acc[i][j], 0, 0, 0);
        __syncthreads();
    }

    #pragma unroll
    for (int j = 0; j < 4; ++j) {
        const int col = N0 + wn + j * 16 + ro;
        const float bias = bih[col];
        #pragma unroll
        for (int i = 0; i < 4; ++i) {
            #pragma unroll
            for (int r = 0; r < 4; ++r) {
                const int rowg = M0 + wm + i * 16 + q * 4 + r;
                out[(size_t)rowg * HH_ + col] = acc[i][j][r] + bias;
            }
        }
    }
}

// ---------------------------------------------------------------------------
// Phase 2: persistent recurrence. 256 blocks x 256 threads = 16 groups x 16
// WGs, plain launch (1 block/CU resources => co-resident). Group g owns
// batches 4g..4g+3; WG wg owns cols j0=64*wg..+63 with its 64x1024 W_hh
// slice held as MFMA B-fragments in VGPRs (128 VGPRs/thread).
//
// ALL cross-WG traffic (h values + flags) uses RELAXED agent-scope atomics:
// these lower to global_load/store sc0 sc1 (coherent-point access, no
// buffer_wbl2 / buffer_inv cache maintenance). R2's 26us/step was the
// acquire/release fences bulk-flushing each XCD L2 every step.
// Ordering: h stores (write-through) -> s_waitcnt vmcnt(0) per wave ->
// __syncthreads -> flag post. Reader: poll flag -> branch retires ->
// h loads (coherent-point) issue after. XCD-placement-independent.
// ---------------------------------------------------------------------------
__global__ __launch_bounds__(256, 1) void rnn_steps(const float* __restrict__ Whh,
                                                    const float* __restrict__ bhh,
                                                    const float* __restrict__ h0,
                                                    float* __restrict__ out,
                                                    int* __restrict__ flags) {
    __shared__ alignas(16) _Float16 h_lds[5 * 1032]; // rows 0..3 batches, row 4 zeros
    __shared__ float red[4][4][64];                  // [k-slice wave][b][j]

    const int tid  = threadIdx.x;
    const int lane = tid & 63;
    const int w    = tid >> 6;             // wave id == k-slice id == epilogue batch id
    const int g    = blockIdx.x >> 4;      // group 0..15
    const int wg   = blockIdx.x & 15;      // wg within group
    const int b0   = g * 4;
    const int j0   = wg * 64;
    const int ro   = lane & 15, q = lane >> 4;
    const int kbase = w * 256;
    const int arow  = (ro < 4) ? ro : 4;   // A rows >=4 read the shared zero row

    // Preload W_hh B-fragments: wf[nt][ks] holds B[k][n] = Whh[j0+n][k],
    // n = nt*16 + ro, k = kbase + ks*32 + q*8 + e.
    half8 wf[4][8];
    #pragma unroll
    for (int nt = 0; nt < 4; ++nt) {
        const float* wrow = Whh + (size_t)(j0 + nt * 16 + ro) * HH_;
        #pragma unroll
        for (int ks = 0; ks < 8; ++ks) {
            const int kc = kbase + ks * 32 + q * 8;
            const float4 w0 = *(const float4*)(wrow + kc);
            const float4 w1 = *(const float4*)(wrow + kc + 4);
            half8 hv;
            hv[0] = (_Float16)w0.x; hv[1] = (_Float16)w0.y;
            hv[2] = (_Float16)w0.z; hv[3] = (_Float16)w0.w;
            hv[4] = (_Float16)w1.x; hv[5] = (_Float16)w1.y;
            hv[6] = (_Float16)w1.z; hv[7] = (_Float16)w1.w;
            wf[nt][ks] = hv;
        }
    }
    const float bhh_r = bhh[j0 + lane];

    for (int i = tid; i < 1032; i += 256) h_lds[4 * 1032 + i] = (_Float16)0.f;
    __syncthreads();

    int* myflags = flags + g * 16 * 16;    // 16 ints (64 B) spacing per WG

    const f32x4 zero4 = {0.f, 0.f, 0.f, 0.f};

    for (int s = 0; s < TT_; ++s) {
        // ---- group barrier: wait until all 16 peers finished step s-1 ----
        if (s > 0) {
            if (w == 0 && lane < 16) {
                while (__hip_atomic_load(myflags + lane * 16, __ATOMIC_RELAXED,
                                         __HIP_MEMORY_SCOPE_AGENT) < s)
                    __builtin_amdgcn_s_sleep(1);
            }
            __syncthreads();
        }

        // ---- stage h_{s-1} into LDS rows 0..3 (coherent-point b64 loads) ----
        {
            const int r  = tid >> 6;           // wave stages one batch row
            const int c0 = tid & 63;           // 8-byte chunk base
            const float* hrow = (s == 0)
                ? (h0 + (size_t)(b0 + r) * HH_)
                : (out + ((size_t)(b0 + r) * TT_ + (s - 1)) * HH_);
            const unsigned long long* hp = (const unsigned long long*)hrow;
            _Float16* drow = h_lds + r * 1032;
            #pragma unroll
            for (int i = 0; i < 8; ++i) {
                const int c = c0 + i * 64;     // chunk -> cols 2c, 2c+1
                unsigned long long v = __hip_atomic_load(
                    (unsigned long long*)(hp + c), __ATOMIC_RELAXED,
                    __HIP_MEMORY_SCOPE_AGENT);
                union { unsigned long long u; float f[2]; } uv; uv.u = v;
                union { _Float16 h[2]; unsigned u; } hv;
                hv.h[0] = (_Float16)uv.f[0]; hv.h[1] = (_Float16)uv.f[1];
                *(unsigned*)(drow + 2 * c) = hv.u;
            }
        }
        // prefetch xp (this thread's own output address; only writer is self)
        const float xpv = out[((size_t)(b0 + w) * TT_ + s) * HH_ + j0 + lane];
        __syncthreads();

        // ---- MFMA: pre[b][j] partials over this wave's 256-wide k-slice ----
        f32x4 acc[4] = {zero4, zero4, zero4, zero4};
        #pragma unroll
        for (int ks = 0; ks < 8; ++ks) {
            const half8 a = *(const half8*)(h_lds + arow * 1032 + kbase + ks * 32 + q * 8);
            #pragma unroll
            for (int nt = 0; nt < 4; ++nt)
                acc[nt] = __builtin_amdgcn_mfma_f32_16x16x32_f16(a, wf[nt][ks], acc[nt], 0, 0, 0);
        }
        // D layout: row=(q*4+reg) => batches 0..3 live in q==0 lanes, col=nt*16+ro
        if (q == 0) {
            #pragma unroll
            for (int nt = 0; nt < 4; ++nt)
                #pragma unroll
                for (int r = 0; r < 4; ++r)
                    red[w][r][nt * 16 + ro] = acc[nt][r];
        }
        __syncthreads();

        // ---- epilogue: thread -> (batch w, col j0+lane) ----
        const float pre  = xpv + bhh_r + red[0][w][lane] + red[1][w][lane]
                                        + red[2][w][lane] + red[3][w][lane];
        const float hnew = tanhf(pre);
        __hip_atomic_store(&out[((size_t)(b0 + w) * TT_ + s) * HH_ + j0 + lane],
                           hnew, __ATOMIC_RELAXED, __HIP_MEMORY_SCOPE_AGENT);

        // drain this wave's write-through stores to the coherent point,
        // join waves, then post -- no cache-maintenance instructions.
        asm volatile("s_waitcnt vmcnt(0)" ::: "memory");
        __syncthreads();
        if (tid == 0)
            __hip_atomic_store(myflags + wg * 16, s + 1, __ATOMIC_RELAXED,
                               __HIP_MEMORY_SCOPE_AGENT);
    }
}

// ---------------------------------------------------------------------------
extern "C" void kernel_launch(void* const* d_in, const int* in_sizes, int n_in,
                              void* d_out, int out_size, void* d_ws, size_t ws_size,
                              hipStream_t stream) {
    (void)in_sizes; (void)n_in; (void)out_size; (void)ws_size;

    const float* x   = (const float*)d_in[0];
    const float* h0  = (const float*)d_in[1];
    const float* Wih = (const float*)d_in[2];
    const float* bih = (const float*)d_in[3];
    const float* Whh = (const float*)d_in[4];
    const float* bhh = (const float*)d_in[5];
    float* out = (float*)d_out;

    // d_ws: flags only -- 256 WGs * 16 ints (64 B spacing) = 16 KB.
    // Poisoned 0xAA => negative ints => "not yet posted" for every step. OK.
    int* flags = (int*)d_ws;

    gemm_xp<<<2048, 256, 0, stream>>>(x, Wih, bih, out);
    rnn_steps<<<256, 256, 0, stream>>>(Whh, bhh, h0, out, flags);
}